// Round 6
// baseline (1017.153 us; speedup 1.0000x reference)
//
#include <hip/hip_runtime.h>
#include <hip/hip_bf16.h>
#include <math.h>

#define S_ 2048
#define B_ 4
#define D_ 1024
#define H_ 16
#define HD_ 64
#define NB_ 127
#define WIN_ 512
#define NSEL_ 16
#define SELBLK_ 64
#define SCALE_ 0.125f

typedef __attribute__((ext_vector_type(8))) short short8;
typedef __attribute__((ext_vector_type(4))) float f32x4;
typedef unsigned short u16;

__device__ inline float bf2f(u16 u) {
    union { unsigned int i; float f; } c; c.i = ((unsigned int)u) << 16; return c.f;
}
__device__ inline u16 f2bf_u(float f) {
    __hip_bfloat16 h = __float2bfloat16(f);
    return *reinterpret_cast<u16*>(&h);
}

// ---------- split fp32 -> bf16 hi/lo (flat, n4 = n/4 float4 groups) ----------
__global__ void split_kernel(const float* __restrict__ src, u16* __restrict__ hi,
                             u16* __restrict__ lo, int n4)
{
    int i = blockIdx.x * 256 + threadIdx.x;
    if (i >= n4) return;
    f32x4 v = ((const f32x4*)src)[i];
    ushort4 h, l;
    u16 h0 = f2bf_u(v[0]), h1 = f2bf_u(v[1]), h2 = f2bf_u(v[2]), h3 = f2bf_u(v[3]);
    h.x = h0; h.y = h1; h.z = h2; h.w = h3;
    ((ushort4*)hi)[i] = h;
    if (lo) {
        l.x = f2bf_u(v[0] - bf2f(h0)); l.y = f2bf_u(v[1] - bf2f(h1));
        l.z = f2bf_u(v[2] - bf2f(h2)); l.w = f2bf_u(v[3] - bf2f(h3));
        ((ushort4*)lo)[i] = l;
    }
}

// ---------- permute w_qkv rows to [q|v|k] grouping + split + bias permute ----------
__global__ void wqkv_prep_kernel(const float* __restrict__ wqkv, const float* __restrict__ bqkv,
                                 u16* __restrict__ whi, u16* __restrict__ wlo,
                                 float* __restrict__ bperm)
{
    int n = blockIdx.x;                  // 0..3071 output row; order q|v|k
    int grp = n >> 10, wd = n & 1023, h = wd >> 6, d = wd & 63;
    int off = (grp == 0) ? 0 : (grp == 1 ? 128 : 64);   // q:0 v:+128 k:+64
    int src = h * 192 + off + d;
    const float* srow = wqkv + (size_t)src * 1024;
    int c = threadIdx.x * 4;
    f32x4 v = *(const f32x4*)(srow + c);
    size_t o = (size_t)n * 1024 + c;
#pragma unroll
    for (int j = 0; j < 4; ++j) {
        u16 hb = f2bf_u(v[j]);
        whi[o + j] = hb;
        wlo[o + j] = f2bf_u(v[j] - bf2f(hb));
    }
    if (threadIdx.x == 0) bperm[n] = bqkv[src];
}

// ---------- split w_c1 (1024 x 1027 fp32) -> 1024 x 1032 bf16 hi/lo (K cols only) ----------
__global__ void w1_split_kernel(const float* __restrict__ w1, u16* __restrict__ hi,
                                u16* __restrict__ lo)
{
    int n = blockIdx.x;
    const float* srow = w1 + (size_t)n * 1027;
    int c = threadIdx.x * 4;
    size_t o = (size_t)n * 1032 + c;
#pragma unroll
    for (int j = 0; j < 4; ++j) {
        float x = srow[c + j];
        u16 hb = f2bf_u(x);
        hi[o + j] = hb;
        lo[o + j] = f2bf_u(x - bf2f(hb));
    }
}

// ---------- Wqm_t[c][d] = mean_h wqkv[(h*192+d)][c] (fp64), bqm[d] ----------
__global__ void wqm_prep_kernel(const float* __restrict__ wqkv, const float* __restrict__ bqkv,
                                double* __restrict__ wqm_t, double* __restrict__ bqm)
{
    int c = blockIdx.x, d = threadIdx.x;
    double s = 0.0;
    for (int h = 0; h < 16; ++h) s += (double)wqkv[(size_t)(h * 192 + d) * 1024 + c];
    wqm_t[(size_t)c * 64 + d] = s * (1.0 / 16.0);
    if (c == 0) {
        double bs = 0.0;
        for (int h = 0; h < 16; ++h) bs += (double)bqkv[h * 192 + d];
        bqm[d] = bs * (1.0 / 16.0);
    }
}

// ---------- w2m_t[c][d] = mean_h w_c2[(h*64+d)][c] (fp64), b2m[d] ----------
__global__ void w2m_prep_kernel(const float* __restrict__ w2, const float* __restrict__ b2,
                                double* __restrict__ w2m_t, double* __restrict__ b2m)
{
    int c = blockIdx.x, d = threadIdx.x;
    double s = 0.0;
    for (int h = 0; h < 16; ++h) s += (double)w2[(size_t)(h * 64 + d) * 1024 + c];
    w2m_t[(size_t)c * 64 + d] = s * (1.0 / 16.0);
    if (c == 0) {
        double bs = 0.0;
        for (int h = 0; h < 16; ++h) bs += (double)b2[h * 64 + d];
        b2m[d] = bs * (1.0 / 16.0);
    }
}

// ---------- x_mean: partial sums over s then reduce (fp64) ----------
__global__ void xmean1_kernel(const float* __restrict__ x, double* __restrict__ part)
{
    int blk = blockIdx.x;                // b*64 + seg (32 s-rows each)
    int b = blk >> 6, seg = blk & 63;
    int t = threadIdx.x;
#pragma unroll
    for (int cc = 0; cc < 4; ++cc) {
        int c = cc * 256 + t;
        double s = 0.0;
        for (int i = 0; i < 32; ++i)
            s += (double)x[((size_t)(seg * 32 + i) * B_ + b) * D_ + c];
        part[(size_t)blk * D_ + c] = s;
    }
}
__global__ void xmean2_kernel(const double* __restrict__ part, double* __restrict__ x_mean)
{
    int b = blockIdx.x;
    int t = threadIdx.x;
#pragma unroll
    for (int cc = 0; cc < 4; ++cc) {
        int c = cc * 256 + t;
        double s = 0.0;
        for (int seg = 0; seg < 64; ++seg) s += part[(size_t)(b * 64 + seg) * D_ + c];
        x_mean[b * D_ + c] = s * (1.0 / S_);
    }
}

// ---------- q_mean_s[b,h*64+d] = x_mean[b] . wqkv_row(h*192+d) + bq (fp64 acc) ----------
__global__ void qms_kernel(const double* __restrict__ x_mean, const float* __restrict__ wqkv,
                           const float* __restrict__ bqkv, float* __restrict__ q_mean_s)
{
    int b = blockIdx.x >> 4, h = blockIdx.x & 15;
    __shared__ double xm[1024];
    __shared__ double red[256];
    int t = threadIdx.x;
    for (int i = t; i < 1024; i += 256) xm[i] = x_mean[b * 1024 + i];
    __syncthreads();
    int d = t & 63, cs = t >> 6;
    const float* wrow = wqkv + (size_t)(h * 192 + d) * 1024 + cs * 256;
    double acc = 0.0;
    for (int c = 0; c < 256; c += 4) {
        f32x4 wv = *(const f32x4*)(wrow + c);
        acc += xm[cs * 256 + c] * wv[0] + xm[cs * 256 + c + 1] * wv[1]
             + xm[cs * 256 + c + 2] * wv[2] + xm[cs * 256 + c + 3] * wv[3];
    }
    red[t] = acc;
    __syncthreads();
    if (t < 64) {
        double s = red[t] + red[64 + t] + red[128 + t] + red[192 + t] + (double)bqkv[h * 192 + t];
        q_mean_s[blockIdx.x * 64 + t] = (float)s;
    }
}

// ---------- q_mean_h[b*S+s][d] = x[s,b] @ Wqm_t + bqm (exact fp64) ----------
__launch_bounds__(256)
__global__ void qmh_kernel(const float* __restrict__ x, const double* __restrict__ wqm_t,
                           const double* __restrict__ bqm, double* __restrict__ qmh)
{
    int blk = blockIdx.x;                // b*64 + chunk (32 s-rows)
    int b = blk >> 6, s0 = (blk & 63) * 32;
    __shared__ double wlds[64 * 64];     // [cc][d]
    __shared__ float xlds[32][68];
    int t = threadIdx.x;
    int d = t & 63, sg = t >> 6;
    double acc[8] = {};
    for (int c0 = 0; c0 < 1024; c0 += 64) {
        __syncthreads();
        for (int i = t; i < 4096; i += 256) wlds[i] = wqm_t[(size_t)c0 * 64 + i];
        for (int i = t; i < 2048; i += 256) {
            int sr = i >> 6, cc = i & 63;
            xlds[sr][cc] = x[((size_t)(s0 + sr) * B_ + b) * D_ + c0 + cc];
        }
        __syncthreads();
#pragma unroll
        for (int ii = 0; ii < 8; ++ii) {
            int sr = sg + 4 * ii;
            double a = 0.0;
            for (int cc = 0; cc < 64; ++cc)
                a += (double)xlds[sr][cc] * wlds[cc * 64 + d];
            acc[ii] += a;
        }
    }
#pragma unroll
    for (int ii = 0; ii < 8; ++ii) {
        int sr = sg + 4 * ii;
        qmh[((size_t)(b * S_ + s0 + sr)) * 64 + d] = acc[ii] + bqm[d];
    }
}

// ---------- ckm[bn][d] = cpre_k[bn] @ w2m_t + b2m (fp64) ----------
__launch_bounds__(256)
__global__ void ckm_kernel(const float* __restrict__ cpre, const double* __restrict__ w2m_t,
                           const double* __restrict__ b2m, double* __restrict__ ckm)
{
    int r0 = blockIdx.x * 16;            // 32 blocks x 16 rows
    __shared__ double wlds[64 * 64];
    __shared__ float xlds[16][68];
    int t = threadIdx.x;
    int d = t & 63, sg = t >> 6;
    double acc[4] = {};
    for (int c0 = 0; c0 < 1024; c0 += 64) {
        __syncthreads();
        for (int i = t; i < 4096; i += 256) wlds[i] = w2m_t[(size_t)c0 * 64 + i];
        for (int i = t; i < 1024; i += 256) {
            int sr = i >> 6, cc = i & 63;
            int row = r0 + sr;
            xlds[sr][cc] = (row < B_ * NB_) ? cpre[(size_t)row * 1024 + c0 + cc] : 0.f;
        }
        __syncthreads();
#pragma unroll
        for (int ii = 0; ii < 4; ++ii) {
            int sr = sg + 4 * ii;
            double a = 0.0;
            for (int cc = 0; cc < 64; ++cc)
                a += (double)xlds[sr][cc] * wlds[cc * 64 + d];
            acc[ii] += a;
        }
    }
#pragma unroll
    for (int ii = 0; ii < 4; ++ii) {
        int row = r0 + sg + 4 * ii;
        if (row < B_ * NB_) ckm[(size_t)row * 64 + d] = acc[ii] + b2m[d];
    }
}

// ---------------- split-bf16 MFMA GEMM: C = A @ B^T (+bias, epilogues) ----------------
// EPI 0: dual bf16 scatter (q|v): gn<1024 -> Oh(q_hi), else Ol(v_hi). gm = s*4+b.
// EPI 3: single bf16 + lo (k): Oh/Ol at gn. gm = s*4+b.
// EPI 1: c1: relu(v+bias+posdot), 16-row sums -> Cf = t16[(b*128+j)*1024+gn]. gm=b*S+s.
// EPI 2: plain: Cf[gm*1024+gn] = v+bias (guard gm<M).
template<int NPASS, int EPI, bool WLO>
__launch_bounds__(256, 2)
__global__ void mgemm_kernel(const u16* __restrict__ Ah, const u16* __restrict__ Al,
                             const u16* __restrict__ Bh, const u16* __restrict__ Bl,
                             int M, int K, int lda, int ldb,
                             const float* __restrict__ bias,
                             float* __restrict__ Cf,
                             u16* __restrict__ Oh, u16* __restrict__ Ol,
                             const float* __restrict__ pos, const float* __restrict__ w1f)
{
    constexpr int NBUF = (NPASS == 3) ? 4 : 2;
    __shared__ u16 lds[NBUF * 4096];
    u16* ldsAh = lds;
    u16* ldsBh = lds + 4096;
    const int tid = threadIdx.x;
    const int w = tid >> 6, lane = tid & 63;
    const int lq = lane & 15, g = lane >> 4;
    const int wm = (w & 1) * 64, wn = (w >> 1) * 64;
    const int bm = blockIdx.x * 128, bn = blockIdx.y * 128;
    const int i4 = lane >> 2;
    const int kc = (lane & 3) ^ ((lane >> 3) & 3);
    f32x4 acc[4][4] = {};

    const u16* gA = Ah + (size_t)(bm + w * 32 + i4) * lda + kc * 8;
    const u16* gB = Bh + (size_t)(bn + w * 32 + i4) * ldb + kc * 8;
    const u16* gAl = nullptr; const u16* gBl = nullptr;
    u16* ldsAl = nullptr; u16* ldsBl = nullptr;
    if (NPASS == 3) {
        gAl = Al + (size_t)(bm + w * 32 + i4) * lda + kc * 8;
        gBl = Bl + (size_t)(bn + w * 32 + i4) * ldb + kc * 8;
        ldsAl = lds + 8192;
        ldsBl = lds + 12288;
    }
    const int sbase = w * 1024 + lane * 8;

    for (int k0 = 0; k0 < K; k0 += 32) {
        __syncthreads();
        short8 a0 = *(const short8*)(gA + k0);
        short8 a1 = *(const short8*)(gA + 16 * lda + k0);
        short8 b0 = *(const short8*)(gB + k0);
        short8 b1 = *(const short8*)(gB + 16 * ldb + k0);
        short8 al0, al1, bl0, bl1;
        if (NPASS == 3) {
            al0 = *(const short8*)(gAl + k0);
            al1 = *(const short8*)(gAl + 16 * lda + k0);
            bl0 = *(const short8*)(gBl + k0);
            bl1 = *(const short8*)(gBl + 16 * ldb + k0);
        }
        *(short8*)(ldsAh + sbase) = a0;
        *(short8*)(ldsAh + sbase + 512) = a1;
        *(short8*)(ldsBh + sbase) = b0;
        *(short8*)(ldsBh + sbase + 512) = b1;
        if (NPASS == 3) {
            *(short8*)(ldsAl + sbase) = al0;
            *(short8*)(ldsAl + sbase + 512) = al1;
            *(short8*)(ldsBl + sbase) = bl0;
            *(short8*)(ldsBl + sbase + 512) = bl1;
        }
        __syncthreads();
        short8 fa[4], fal[4];
#pragma unroll
        for (int i = 0; i < 4; ++i) {
            int row = wm + i * 16 + lq;
            int sl = row * 4 + (g ^ ((row >> 1) & 3));
            fa[i] = *(const short8*)(ldsAh + sl * 8);
            if (NPASS == 3) fal[i] = *(const short8*)(ldsAl + sl * 8);
        }
#pragma unroll
        for (int jb = 0; jb < 4; ++jb) {
            int row = wn + jb * 16 + lq;
            int sl = row * 4 + (g ^ ((row >> 1) & 3));
            short8 fb = *(const short8*)(ldsBh + sl * 8);
            short8 fbl;
            if (NPASS == 3) fbl = *(const short8*)(ldsBl + sl * 8);
#pragma unroll
            for (int i = 0; i < 4; ++i) {
                acc[i][jb] = __builtin_amdgcn_mfma_f32_16x16x32_bf16(fa[i], fb, acc[i][jb], 0, 0, 0);
                if (NPASS == 3) {
                    acc[i][jb] = __builtin_amdgcn_mfma_f32_16x16x32_bf16(fal[i], fb, acc[i][jb], 0, 0, 0);
                    acc[i][jb] = __builtin_amdgcn_mfma_f32_16x16x32_bf16(fa[i], fbl, acc[i][jb], 0, 0, 0);
                }
            }
        }
    }
    if (EPI == 1) {
        // relu + 16-row partial sums -> t16 (one wave owns each 16-row group)
#pragma unroll
        for (int jb = 0; jb < 4; ++jb) {
            int gn = bn + wn + jb * 16 + lq;
            float bz = bias[gn];
            float w0 = w1f[(size_t)gn * 1027 + 1024];
            float w1 = w1f[(size_t)gn * 1027 + 1025];
            float w2 = w1f[(size_t)gn * 1027 + 1026];
#pragma unroll
            for (int i = 0; i < 4; ++i) {
                int gm0 = bm + wm + i * 16 + g * 4;
                int bb = gm0 >> 11;
                int jj = (gm0 & (S_ - 1)) >> 4;
                float s4 = 0.f;
#pragma unroll
                for (int r = 0; r < 4; ++r) {
                    int st = (gm0 + r) & (S_ - 1);
                    float v = acc[i][jb][r] + bz
                            + pos[st * 3 + 0] * w0 + pos[st * 3 + 1] * w1
                            + pos[st * 3 + 2] * w2;
                    s4 += fmaxf(v, 0.f);
                }
                s4 += __shfl_xor(s4, 16, 64);
                s4 += __shfl_xor(s4, 32, 64);
                if (g == 0) Cf[((size_t)(bb * 128 + jj)) * 1024 + gn] = s4;
            }
        }
    } else {
#pragma unroll
        for (int i = 0; i < 4; ++i) {
#pragma unroll
            for (int jb = 0; jb < 4; ++jb) {
#pragma unroll
                for (int r = 0; r < 4; ++r) {
                    int gm = bm + wm + i * 16 + g * 4 + r;
                    int gn = bn + wn + jb * 16 + lq;
                    float v = acc[i][jb][r] + bias[gn];
                    if (EPI == 0) {
                        int s = gm >> 2, bb = gm & 3;
                        u16 hb = f2bf_u(v);
                        if (gn < 1024) Oh[((size_t)(bb * S_ + s)) * D_ + gn] = hb;
                        else Ol[((size_t)(bb * S_ + s)) * D_ + (gn - 1024)] = hb;
                    } else if (EPI == 3) {
                        int s = gm >> 2, bb = gm & 3;
                        size_t idx = ((size_t)(bb * S_ + s)) * D_ + gn;
                        u16 hb = f2bf_u(v);
                        Oh[idx] = hb;
                        if (WLO) Ol[idx] = f2bf_u(v - bf2f(hb));
                    } else {
                        if (gm < M) Cf[(size_t)gm * 1024 + gn] = v;
                    }
                }
            }
        }
    }
}

// cpre[b,n,c] = (t16[b][n] + t16[b][n+1]) / 32
__global__ void t16c_kernel(const float* __restrict__ t16, float* __restrict__ cpre)
{
    int bn = blockIdx.x;
    int b = bn / NB_, n = bn % NB_;
    for (int c = threadIdx.x; c < 1024; c += 256)
        cpre[(size_t)bn * 1024 + c] =
            (t16[((size_t)(b * 128 + n)) * 1024 + c] +
             t16[((size_t)(b * 128 + n + 1)) * 1024 + c]) * (1.f / 32.f);
}

// v_t[b][h][d][s] = transpose of v_hi[b][s][h*64+d] (bf16 -> bf16)
__launch_bounds__(256)
__global__ void vt_kernel(const u16* __restrict__ v_hi, u16* __restrict__ v_t)
{
    __shared__ u16 tile[64][68];
    int blk = blockIdx.x;
    int b = blk >> 9, h = (blk >> 5) & 15, s0 = (blk & 31) * 64;
    int tid = threadIdx.x;
#pragma unroll
    for (int i = 0; i < 16; ++i) {
        int idx = tid + i * 256;
        int r = idx >> 6, d = idx & 63;
        tile[r][d] = v_hi[((size_t)(b * S_ + s0 + r)) * D_ + h * HD_ + d];
    }
    __syncthreads();
#pragma unroll
    for (int i = 0; i < 16; ++i) {
        int idx = tid + i * 256;
        int d = idx >> 6, cc = idx & 63;
        v_t[((size_t)((b * H_ + h) * HD_ + d)) * S_ + s0 + cc] = tile[cc][d];
    }
}

// out_cmp[b,h,:] = softmax(q_mean_s . cmp_k * SCALE) @ cmp_v
__launch_bounds__(128)
__global__ void out_cmp_kernel(const float* __restrict__ q_mean_s, const float* __restrict__ cmp_k,
                               const float* __restrict__ cmp_v, float* __restrict__ out_cmp)
{
    int bh = blockIdx.x;
    int b = bh >> 4, h = bh & 15;
    int t = threadIdx.x;
    __shared__ float qv[64];
    __shared__ float pv[128];
    __shared__ float red[128];
    if (t < 64) qv[t] = q_mean_s[bh * 64 + t];
    __syncthreads();
    float sc = -1e30f;
    if (t < NB_) {
        const float* kr = &cmp_k[((size_t)b * NB_ + t) * D_ + h * HD_];
        float sum = 0.f;
        for (int d = 0; d < 64; ++d) sum = fmaf(qv[d], kr[d], sum);
        sc = sum * SCALE_;
    }
    red[t] = sc;
    __syncthreads();
    for (int off = 64; off > 0; off >>= 1) {
        if (t < off) red[t] = fmaxf(red[t], red[t + off]);
        __syncthreads();
    }
    float mx = red[0];
    __syncthreads();
    float e = (t < NB_) ? __expf(sc - mx) : 0.f;
    pv[t] = e;
    red[t] = e;
    __syncthreads();
    for (int off = 64; off > 0; off >>= 1) {
        if (t < off) red[t] += red[t + off];
        __syncthreads();
    }
    float sm = red[0];
    __syncthreads();
    if (t < 64) {
        float o = 0.f;
        for (int n = 0; n < NB_; ++n)
            o = fmaf(pv[n], cmp_v[((size_t)b * NB_ + n) * D_ + h * HD_ + t], o);
        out_cmp[bh * 64 + t] = o / sm;
    }
}

// imp_all[b,n,s] = softmax_n(q_mean_h[b,s] . ckm[b,n] * SCALE)  fp64
__launch_bounds__(128)
__global__ void imp1_kernel(const double* __restrict__ q_mean_h, const double* __restrict__ ckm,
                            double* __restrict__ imp_all)
{
    int bs = blockIdx.x;
    int b = bs >> 11, s = bs & (S_ - 1);
    int t = threadIdx.x;
    __shared__ double qv[64];
    __shared__ double red[128];
    if (t < 64) qv[t] = q_mean_h[(size_t)bs * 64 + t];
    __syncthreads();
    double sc = -1e300;
    if (t < NB_) {
        const double* kr = &ckm[(b * NB_ + t) * 64];
        double sum = 0.0;
        for (int d = 0; d < 64; ++d) sum = fma(qv[d], kr[d], sum);
        sc = sum * (double)SCALE_;
    }
    red[t] = sc;
    __syncthreads();
    for (int off = 64; off > 0; off >>= 1) {
        if (t < off) red[t] = fmax(red[t], red[t + off]);
        __syncthreads();
    }
    double mx = red[0];
    __syncthreads();
    double e = (t < NB_) ? exp(sc - mx) : 0.0;
    red[t] = e;
    __syncthreads();
    for (int off = 64; off > 0; off >>= 1) {
        if (t < off) red[t] += red[t + off];
        __syncthreads();
    }
    double sm = red[0];
    if (t < NB_) imp_all[((size_t)(b * NB_ + t)) * S_ + s] = e / sm;
}

// imp[b,n] = mean_s imp_all[b,n,s]  fp64
__global__ void imp2_kernel(const double* __restrict__ imp_all, double* __restrict__ imp)
{
    int bn = blockIdx.x;
    int t = threadIdx.x;
    double sum = 0.0;
    for (int s = t; s < S_; s += 256) sum += imp_all[(size_t)bn * S_ + s];
    __shared__ double red[256];
    red[t] = sum;
    __syncthreads();
    for (int off = 128; off > 0; off >>= 1) {
        if (t < off) red[t] += red[t + off];
        __syncthreads();
    }
    if (t == 0) imp[bn] = red[0] * (1.0 / S_);
}

// exact top-16 per batch, stable (lowest index wins ties)
__global__ void topk_kernel(const double* __restrict__ imp, int* __restrict__ topb)
{
    int b = threadIdx.x;
    if (b >= B_) return;
    unsigned long long used0 = 0ull, used1 = 0ull;
    for (int m = 0; m < NSEL_; ++m) {
        double best = -1e300;
        int bi = 0;
        for (int n = 0; n < NB_; ++n) {
            bool u = (n < 64) ? ((used0 >> n) & 1ull) : ((used1 >> (n - 64)) & 1ull);
            double v = imp[b * NB_ + n];
            if (!u && v > best) { best = v; bi = n; }
        }
        if (bi < 64) used0 |= 1ull << bi; else used1 |= 1ull << (bi - 64);
        topb[b * NSEL_ + m] = bi;
    }
}

// ---------------- MFMA flash attention (bf16 inputs) ----------------
template<int NCH, int MODE>
__launch_bounds__(256, 4)
__global__ void attn_mfma_kernel(const u16* __restrict__ q_hi, const u16* __restrict__ k_hi,
                                 const u16* __restrict__ v_t,
                                 const int* __restrict__ topb, float* __restrict__ outp)
{
    __shared__ __attribute__((aligned(16))) char smem[27648];
    u16* klds = (u16*)smem;
    u16* vlds = (u16*)(smem + 9216);
    u16* plds = (u16*)(smem + 18432);
    __shared__ int selb[NSEL_];
    const int tid = threadIdx.x;
    const int wid = tid >> 6, lane = tid & 63;
    const int lq = lane & 15, g = lane >> 4;
    const int blk = blockIdx.x;
    const int b = blk >> 9;
    const int h = (blk >> 5) & 15;
    const int q0 = (blk & 31) * 64 + wid * 16;
    u16* pw = plds + wid * 16 * 72;

    if (MODE == 1 && tid < NSEL_) selb[tid] = topb[b * NSEL_ + tid];

    short8 qfrag[2];
    {
        const u16* qp = q_hi + ((size_t)(b * S_ + q0 + lq)) * D_ + h * HD_ + g * 8;
        qfrag[0] = *(const short8*)qp;
        qfrag[1] = *(const short8*)(qp + 32);
    }
    f32x4 oacc[4] = {};
    float rm = -1e30f, rl = 0.f;

    for (int c = 0; c < NCH; ++c) {
        __syncthreads();
        int t0;
        bool clamped = false;
        if (MODE == 0) t0 = S_ - NCH * 64 + c * 64;
        else { t0 = selb[c] * SELBLK_; clamped = (t0 >= S_); }
#pragma unroll
        for (int it = 0; it < 2; ++it) {
            int idx = tid + it * 256;
            int r = idx >> 3, cc = idx & 7;
            int tk = t0 + r; if (tk > S_ - 1) tk = S_ - 1;
            *(short8*)(klds + r * 72 + cc * 8) =
                *(const short8*)(k_hi + ((size_t)(b * S_ + tk)) * D_ + h * HD_ + cc * 8);
            const u16* vrow = v_t + ((size_t)((b * H_ + h) * HD_ + r)) * S_;
            short8 vv;
            if (!clamped) {
                vv = *(const short8*)(vrow + t0 + cc * 8);
            } else {
                short x = (short)vrow[S_ - 1];
                vv = (short8){x, x, x, x, x, x, x, x};
            }
            *(short8*)(vlds + r * 72 + cc * 8) = vv;
        }
        __syncthreads();
        f32x4 st[4];
#pragma unroll
        for (int sub = 0; sub < 4; ++sub) {
            short8 ka0 = *(const short8*)(klds + (sub * 16 + lq) * 72 + g * 8);
            short8 ka1 = *(const short8*)(klds + (sub * 16 + lq) * 72 + 32 + g * 8);
            f32x4 acc = {};
            acc = __builtin_amdgcn_mfma_f32_16x16x32_bf16(ka0, qfrag[0], acc, 0, 0, 0);
            acc = __builtin_amdgcn_mfma_f32_16x16x32_bf16(ka1, qfrag[1], acc, 0, 0, 0);
            st[sub] = acc;
        }
        float mx = -1e30f;
#pragma unroll
        for (int sub = 0; sub < 4; ++sub)
#pragma unroll
            for (int r = 0; r < 4; ++r) {
                st[sub][r] *= SCALE_;
                mx = fmaxf(mx, st[sub][r]);
            }
        mx = fmaxf(mx, __shfl_xor(mx, 16, 64));
        mx = fmaxf(mx, __shfl_xor(mx, 32, 64));
        float nm = fmaxf(rm, mx);
        float alpha = __expf(rm - nm);
        rm = nm;
        float ps = 0.f;
#pragma unroll
        for (int sub = 0; sub < 4; ++sub)
#pragma unroll
            for (int r = 0; r < 4; ++r) {
                float p = __expf(st[sub][r] - nm);
                st[sub][r] = p;
                ps += p;
            }
        ps += __shfl_xor(ps, 16, 64);
        ps += __shfl_xor(ps, 32, 64);
        rl = rl * alpha + ps;
#pragma unroll
        for (int m = 0; m < 4; ++m)
#pragma unroll
            for (int r = 0; r < 4; ++r) oacc[m][r] *= alpha;
#pragma unroll
        for (int sub = 0; sub < 4; ++sub)
#pragma unroll
            for (int r = 0; r < 4; ++r)
                pw[lq * 72 + sub * 16 + g * 4 + r] = f2bf_u(st[sub][r]);
        short8 pf0 = *(const short8*)(pw + lq * 72 + g * 8);
        short8 pf1 = *(const short8*)(pw + lq * 72 + 32 + g * 8);
#pragma unroll
        for (int m = 0; m < 4; ++m) {
            short8 va0 = *(const short8*)(vlds + (m * 16 + lq) * 72 + g * 8);
            short8 va1 = *(const short8*)(vlds + (m * 16 + lq) * 72 + 32 + g * 8);
            oacc[m] = __builtin_amdgcn_mfma_f32_16x16x32_bf16(va0, pf0, oacc[m], 0, 0, 0);
            oacc[m] = __builtin_amdgcn_mfma_f32_16x16x32_bf16(va1, pf1, oacc[m], 0, 0, 0);
        }
    }
    __syncthreads();
    float invl = 1.f / rl;
    float* obuf = (float*)smem + wid * (16 * 68);
#pragma unroll
    for (int m = 0; m < 4; ++m)
#pragma unroll
        for (int r = 0; r < 4; ++r)
            obuf[lq * 68 + m * 16 + g * 4 + r] = oacc[m][r] * invl;
    {
        int q = lane >> 2, seg = lane & 3;
        const float* row = obuf + q * 68 + seg * 16;
        float* dst = outp + ((size_t)(b * S_ + q0 + q)) * D_ + h * HD_ + seg * 16;
#pragma unroll
        for (int k = 0; k < 4; ++k)
            *(f32x4*)(dst + k * 4) = *(const f32x4*)(row + k * 4);
    }
}

// gates = softmax([oc,osl,ow] @ w_g.T + b_g); out = g0*oc+g1*osl+g2*ow
__launch_bounds__(128)
__global__ void gate_kernel(const float* __restrict__ out_cmp, const float* __restrict__ o_slc,
                            const float* __restrict__ o_win, const float* __restrict__ w_g,
                            const float* __restrict__ b_g, float* __restrict__ outp)
{
    int bs = blockIdx.x;
    int b = bs >> 11;
    int t = threadIdx.x;
    float oc_r[8], os_r[8], ow_r[8];
    float g0 = 0.f, g1 = 0.f, g2 = 0.f;
#pragma unroll
    for (int i = 0; i < 8; ++i) {
        int c = t + i * 128;
        float oc = out_cmp[(b * H_ + (c >> 6)) * 64 + (c & 63)];
        float os = o_slc[(size_t)bs * D_ + c];
        float ow = o_win[(size_t)bs * D_ + c];
        oc_r[i] = oc; os_r[i] = os; ow_r[i] = ow;
        g0 += w_g[c] * oc + w_g[1024 + c] * os + w_g[2048 + c] * ow;
        g1 += w_g[3072 + c] * oc + w_g[3072 + 1024 + c] * os + w_g[3072 + 2048 + c] * ow;
        g2 += w_g[6144 + c] * oc + w_g[6144 + 1024 + c] * os + w_g[6144 + 2048 + c] * ow;
    }
    __shared__ float red[3][128];
    red[0][t] = g0; red[1][t] = g1; red[2][t] = g2;
    __syncthreads();
    for (int off = 64; off > 0; off >>= 1) {
        if (t < off) {
            red[0][t] += red[0][t + off];
            red[1][t] += red[1][t + off];
            red[2][t] += red[2][t + off];
        }
        __syncthreads();
    }
    float a0 = red[0][0] + b_g[0], a1 = red[1][0] + b_g[1], a2 = red[2][0] + b_g[2];
    float m = fmaxf(a0, fmaxf(a1, a2));
    float e0 = __expf(a0 - m), e1 = __expf(a1 - m), e2 = __expf(a2 - m);
    float inv = 1.f / (e0 + e1 + e2);
    e0 *= inv; e1 *= inv; e2 *= inv;
#pragma unroll
    for (int i = 0; i < 8; ++i) {
        int c = t + i * 128;
        outp[(size_t)bs * D_ + c] = e0 * oc_r[i] + e1 * os_r[i] + e2 * ow_r[i];
    }
}

extern "C" void kernel_launch(void* const* d_in, const int* in_sizes, int n_in,
                              void* d_out, int out_size, void* d_ws, size_t ws_size,
                              hipStream_t stream)
{
    const float* x     = (const float*)d_in[0];
    const float* pos   = (const float*)d_in[1];
    const float* w_qkv = (const float*)d_in[2];
    const float* b_qkv = (const float*)d_in[3];
    const float* w_c1  = (const float*)d_in[4];
    const float* b_c1  = (const float*)d_in[5];
    const float* w_c2  = (const float*)d_in[6];
    const float* b_c2  = (const float*)d_in[7];
    const float* w_g   = (const float*)d_in[8];
    const float* b_g   = (const float*)d_in[9];
    float* out = (float*)d_out;
    (void)in_sizes; (void)n_in; (void)out_size; (void)ws_size;

    char* wp = (char*)d_ws;
    size_t off = 0;
    auto alloc = [&](size_t nbytes) -> void* {
        void* p = (void*)(wp + off);
        off += ((nbytes + 255) / 256) * 256;
        return p;
    };
    const size_t NTOK = (size_t)B_ * S_ * D_;
    float* o_slc = (float*)alloc(NTOK * 4);
    float* o_win = (float*)alloc(NTOK * 4);            // early life: imp_all (fp64)
    double* imp_all = (double*)o_win;
    u16* q_hi = (u16*)alloc(NTOK * 2);
    u16* k_hi = (u16*)alloc(NTOK * 2);
    u16* k_lo = (u16*)alloc(NTOK * 2);
    u16* v_hi = (u16*)alloc(NTOK * 2);
    u16* x_hi = (u16*)alloc(NTOK * 2);                 // late life: v_t
    u16* v_t  = x_hi;
    u16* x_lo = (u16*)alloc(NTOK * 2);                 // late life: misc region
    // malloc2 region aliases x_lo. INVARIANT: nothing here may be WRITTEN
    // before the NPASS3 k-GEMM (the last reader of x_lo) has run.
    char* mp = (char*)x_lo;
    size_t moff = 0;
    auto malloc2 = [&](size_t nbytes) -> void* {
        void* p = (void*)(mp + moff);
        moff += ((nbytes + 255) / 256) * 256;
        return p;
    };
    const size_t NCMP = (size_t)B_ * NB_ * D_;
    float* cpre_k = (float*)malloc2(NCMP * 4);
    float* cpre_v = (float*)malloc2(NCMP * 4);
    float* cmp_k  = (float*)malloc2(NCMP * 4);
    float* cmp_v  = (float*)malloc2(NCMP * 4);
    u16* cpk_hi = (u16*)malloc2(NCMP * 2);
    u16* cpv_hi = (u16*)malloc2(NCMP * 2);
    float*  t16  = (float*)malloc2((size_t)B_ * 128 * 1024 * 4);
    double* ckm  = (double*)malloc2(B_ * NB_ * 64 * 8);
    float*  ocmp = (float*)malloc2(B_ * H_ * 64 * 4);
    double* imp  = (double*)malloc2(B_ * NB_ * 8);
    int*    topb = (int*)malloc2(B_ * NSEL_ * 4);
    malloc2(65536);
    // weights / fp64 helpers (live across whole pipeline; written in step 0 —
    // must NOT alias x_lo). q_mean_s lives here (R5 bug: it was in malloc2 but
    // is written by qms_kernel BEFORE the k-GEMM reads x_lo).
    u16* wq_hi = (u16*)alloc((size_t)3072 * 1024 * 2);
    u16* wq_lo = (u16*)alloc((size_t)3072 * 1024 * 2);
    float* b_perm = (float*)alloc(3072 * 4);
    u16* w1h = (u16*)alloc((size_t)1024 * 1032 * 2);
    u16* w1l = (u16*)alloc((size_t)1024 * 1032 * 2);
    u16* w2h = (u16*)alloc((size_t)1024 * 1024 * 2);
    double* q_mean_h = (double*)alloc((size_t)B_ * S_ * 64 * 8);
    double* wqm_t = (double*)alloc((size_t)1024 * 64 * 8);
    double* bqm   = (double*)alloc(64 * 8);
    double* w2m_t = (double*)alloc((size_t)1024 * 64 * 8);
    double* b2m   = (double*)alloc(64 * 8);
    double* x_mean = (double*)alloc((size_t)B_ * 1024 * 8);
    double* xpart  = (double*)alloc((size_t)B_ * 64 * 1024 * 8);
    float*  q_mean_s = (float*)alloc(B_ * H_ * 64 * 4);
    alloc(65536);

    dim3 blk(256);
    // 0. weight prep + splits + fp64 means helpers
    split_kernel<<<(int)(NTOK / 1024), blk, 0, stream>>>(x, x_hi, x_lo, (int)(NTOK / 4));
    wqkv_prep_kernel<<<3072, blk, 0, stream>>>(w_qkv, b_qkv, wq_hi, wq_lo, b_perm);
    w1_split_kernel<<<1024, blk, 0, stream>>>(w_c1, w1h, w1l);
    split_kernel<<<1024, blk, 0, stream>>>(w_c2, w2h, nullptr, 1024 * 1024 / 4);
    wqm_prep_kernel<<<1024, 64, 0, stream>>>(w_qkv, b_qkv, wqm_t, bqm);
    w2m_prep_kernel<<<1024, 64, 0, stream>>>(w_c2, b_c2, w2m_t, b2m);
    xmean1_kernel<<<B_ * 64, blk, 0, stream>>>(x, xpart);
    xmean2_kernel<<<B_, blk, 0, stream>>>(xpart, x_mean);
    qms_kernel<<<B_ * H_, blk, 0, stream>>>(x_mean, w_qkv, b_qkv, q_mean_s);
    qmh_kernel<<<B_ * 64, blk, 0, stream>>>(x, wqm_t, bqm, q_mean_h);
    // 1. QKV projection: q|v fused NPASS1, k NPASS3
    mgemm_kernel<1, 0, false><<<dim3(64, 16), blk, 0, stream>>>(
        x_hi, nullptr, wq_hi, nullptr, S_ * B_, 1024, 1024, 1024,
        b_perm, nullptr, q_hi, v_hi, nullptr, nullptr);
    mgemm_kernel<3, 3, true><<<dim3(64, 8), blk, 0, stream>>>(
        x_hi, x_lo, wq_hi + (size_t)2048 * 1024, wq_lo + (size_t)2048 * 1024, S_ * B_, 1024, 1024, 1024,
        b_perm + 2048, nullptr, k_hi, k_lo, nullptr, nullptr);
    // 1b. V^T for attention (x_hi dead -> v_t alias)
    vt_kernel<<<2048, blk, 0, stream>>>(v_hi, v_t);
    // 2. compression: c1 with fused relu+16-row-sum epilogue -> t16 -> cpre
    mgemm_kernel<3, 1, false><<<dim3(64, 8), blk, 0, stream>>>(
        k_hi, k_lo, w1h, w1l, B_ * S_, 1024, 1024, 1032,
        b_c1, t16, nullptr, nullptr, pos, w_c1);
    t16c_kernel<<<B_ * NB_, blk, 0, stream>>>(t16, cpre_k);
    mgemm_kernel<1, 1, false><<<dim3(64, 8), blk, 0, stream>>>(
        v_hi, nullptr, w1h, nullptr, B_ * S_, 1024, 1024, 1032,
        b_c1, t16, nullptr, nullptr, pos, w_c1);
    t16c_kernel<<<B_ * NB_, blk, 0, stream>>>(t16, cpre_v);
    split_kernel<<<508, blk, 0, stream>>>(cpre_k, cpk_hi, nullptr, (int)(NCMP / 4));
    split_kernel<<<508, blk, 0, stream>>>(cpre_v, cpv_hi, nullptr, (int)(NCMP / 4));
    mgemm_kernel<1, 2, false><<<dim3(4, 8), blk, 0, stream>>>(
        cpk_hi, nullptr, w2h, nullptr, B_ * NB_, 1024, 1024, 1024,
        b_c2, cmp_k, nullptr, nullptr, nullptr, nullptr);
    mgemm_kernel<1, 2, false><<<dim3(4, 8), blk, 0, stream>>>(
        cpv_hi, nullptr, w2h, nullptr, B_ * NB_, 1024, 1024, 1024,
        b_c2, cmp_v, nullptr, nullptr, nullptr, nullptr);
    // 3. ckm (fp64, from cpre_k directly)
    ckm_kernel<<<32, blk, 0, stream>>>(cpre_k, w2m_t, b2m, ckm);
    // 4. compressed-branch attention + importance (fp64) + top-k
    out_cmp_kernel<<<B_ * H_, 128, 0, stream>>>(q_mean_s, cmp_k, cmp_v, ocmp);
    imp1_kernel<<<B_ * S_, 128, 0, stream>>>(q_mean_h, ckm, imp_all);
    imp2_kernel<<<B_ * NB_, 256, 0, stream>>>(imp_all, imp);
    topk_kernel<<<1, 64, 0, stream>>>(imp, topb);
    // 5. selected + window attention (MFMA flash, bf16)
    attn_mfma_kernel<16, 1><<<2048, blk, 0, stream>>>(q_hi, k_hi, v_t, topb, o_slc);
    attn_mfma_kernel<8, 0><<<2048, blk, 0, stream>>>(q_hi, k_hi, v_t, nullptr, o_win);
    // 6. gate + combine
    gate_kernel<<<B_ * S_, 128, 0, stream>>>(ocmp, o_slc, o_win, w_g, b_g, out);
}

// Round 7
// 876.166 us; speedup vs baseline: 1.1609x; 1.1609x over previous
//
#include <hip/hip_runtime.h>
#include <hip/hip_bf16.h>
#include <math.h>

#define S_ 2048
#define B_ 4
#define D_ 1024
#define H_ 16
#define HD_ 64
#define NB_ 127
#define WIN_ 512
#define NSEL_ 16
#define SELBLK_ 64
#define SCALE_ 0.125f

typedef __attribute__((ext_vector_type(8))) short short8;
typedef __attribute__((ext_vector_type(4))) float f32x4;
typedef unsigned short u16;

__device__ inline float bf2f(u16 u) {
    union { unsigned int i; float f; } c; c.i = ((unsigned int)u) << 16; return c.f;
}
__device__ inline u16 f2bf_u(float f) {
    __hip_bfloat16 h = __float2bfloat16(f);
    return *reinterpret_cast<u16*>(&h);
}

// ---------- split fp32 -> bf16 hi/lo (flat, n4 = n/4 float4 groups) ----------
__global__ void split_kernel(const float* __restrict__ src, u16* __restrict__ hi,
                             u16* __restrict__ lo, int n4)
{
    int i = blockIdx.x * 256 + threadIdx.x;
    if (i >= n4) return;
    f32x4 v = ((const f32x4*)src)[i];
    ushort4 h, l;
    u16 h0 = f2bf_u(v[0]), h1 = f2bf_u(v[1]), h2 = f2bf_u(v[2]), h3 = f2bf_u(v[3]);
    h.x = h0; h.y = h1; h.z = h2; h.w = h3;
    ((ushort4*)hi)[i] = h;
    if (lo) {
        l.x = f2bf_u(v[0] - bf2f(h0)); l.y = f2bf_u(v[1] - bf2f(h1));
        l.z = f2bf_u(v[2] - bf2f(h2)); l.w = f2bf_u(v[3] - bf2f(h3));
        ((ushort4*)lo)[i] = l;
    }
}

// ---------- permute w_qkv rows to [q|v|k] grouping + split + bias permute ----------
__global__ void wqkv_prep_kernel(const float* __restrict__ wqkv, const float* __restrict__ bqkv,
                                 u16* __restrict__ whi, u16* __restrict__ wlo,
                                 float* __restrict__ bperm)
{
    int n = blockIdx.x;                  // 0..3071 output row; order q|v|k
    int grp = n >> 10, wd = n & 1023, h = wd >> 6, d = wd & 63;
    int off = (grp == 0) ? 0 : (grp == 1 ? 128 : 64);   // q:0 v:+128 k:+64
    int src = h * 192 + off + d;
    const float* srow = wqkv + (size_t)src * 1024;
    int c = threadIdx.x * 4;
    f32x4 v = *(const f32x4*)(srow + c);
    size_t o = (size_t)n * 1024 + c;
#pragma unroll
    for (int j = 0; j < 4; ++j) {
        u16 hb = f2bf_u(v[j]);
        whi[o + j] = hb;
        wlo[o + j] = f2bf_u(v[j] - bf2f(hb));
    }
    if (threadIdx.x == 0) bperm[n] = bqkv[src];
}

// ---------- split w_c1 (1024 x 1027 fp32) -> 1024 x 1032 bf16 hi/lo (K cols only) ----------
__global__ void w1_split_kernel(const float* __restrict__ w1, u16* __restrict__ hi,
                                u16* __restrict__ lo)
{
    int n = blockIdx.x;
    const float* srow = w1 + (size_t)n * 1027;
    int c = threadIdx.x * 4;
    size_t o = (size_t)n * 1032 + c;
#pragma unroll
    for (int j = 0; j < 4; ++j) {
        float x = srow[c + j];
        u16 hb = f2bf_u(x);
        hi[o + j] = hb;
        lo[o + j] = f2bf_u(x - bf2f(hb));
    }
}

// ---------- wqm_f[c][d] = mean_h wqkv[(h*192+d)][c] (fp32), bqm[d] fp64 ----------
__global__ void wqm_prep_kernel(const float* __restrict__ wqkv, const float* __restrict__ bqkv,
                                float* __restrict__ wqm_f, double* __restrict__ bqm)
{
    int c = blockIdx.x, d = threadIdx.x;
    double s = 0.0;
    for (int h = 0; h < 16; ++h) s += (double)wqkv[(size_t)(h * 192 + d) * 1024 + c];
    wqm_f[(size_t)c * 64 + d] = (float)(s * (1.0 / 16.0));
    if (c == 0) {
        double bs = 0.0;
        for (int h = 0; h < 16; ++h) bs += (double)bqkv[h * 192 + d];
        bqm[d] = bs * (1.0 / 16.0);
    }
}

// ---------- w2m_f[c][d] = mean_h w_c2[(h*64+d)][c] (fp32), b2m[d] fp64 ----------
__global__ void w2m_prep_kernel(const float* __restrict__ w2, const float* __restrict__ b2,
                                float* __restrict__ w2m_f, double* __restrict__ b2m)
{
    int c = blockIdx.x, d = threadIdx.x;
    double s = 0.0;
    for (int h = 0; h < 16; ++h) s += (double)w2[(size_t)(h * 64 + d) * 1024 + c];
    w2m_f[(size_t)c * 64 + d] = (float)(s * (1.0 / 16.0));
    if (c == 0) {
        double bs = 0.0;
        for (int h = 0; h < 16; ++h) bs += (double)b2[h * 64 + d];
        b2m[d] = bs * (1.0 / 16.0);
    }
}

// ---------- x_mean: partial sums over s then reduce (fp64) ----------
__global__ void xmean1_kernel(const float* __restrict__ x, double* __restrict__ part)
{
    int blk = blockIdx.x;                // b*64 + seg (32 s-rows each)
    int b = blk >> 6, seg = blk & 63;
    int t = threadIdx.x;
#pragma unroll
    for (int cc = 0; cc < 4; ++cc) {
        int c = cc * 256 + t;
        double s = 0.0;
        for (int i = 0; i < 32; ++i)
            s += (double)x[((size_t)(seg * 32 + i) * B_ + b) * D_ + c];
        part[(size_t)blk * D_ + c] = s;
    }
}
__global__ void xmean2_kernel(const double* __restrict__ part, double* __restrict__ x_mean)
{
    int b = blockIdx.x;
    int t = threadIdx.x;
#pragma unroll
    for (int cc = 0; cc < 4; ++cc) {
        int c = cc * 256 + t;
        double s = 0.0;
        for (int seg = 0; seg < 64; ++seg) s += part[(size_t)(b * 64 + seg) * D_ + c];
        x_mean[b * D_ + c] = s * (1.0 / S_);
    }
}

// ---------- q_mean_s[b,h*64+d] = x_mean[b] . wqkv_row(h*192+d) + bq (fp64 acc) ----------
__global__ void qms_kernel(const double* __restrict__ x_mean, const float* __restrict__ wqkv,
                           const float* __restrict__ bqkv, float* __restrict__ q_mean_s)
{
    int b = blockIdx.x >> 4, h = blockIdx.x & 15;
    __shared__ double xm[1024];
    __shared__ double red[256];
    int t = threadIdx.x;
    for (int i = t; i < 1024; i += 256) xm[i] = x_mean[b * 1024 + i];
    __syncthreads();
    int d = t & 63, cs = t >> 6;
    const float* wrow = wqkv + (size_t)(h * 192 + d) * 1024 + cs * 256;
    double acc = 0.0;
    for (int c = 0; c < 256; c += 4) {
        f32x4 wv = *(const f32x4*)(wrow + c);
        acc += xm[cs * 256 + c] * wv[0] + xm[cs * 256 + c + 1] * wv[1]
             + xm[cs * 256 + c + 2] * wv[2] + xm[cs * 256 + c + 3] * wv[3];
    }
    red[t] = acc;
    __syncthreads();
    if (t < 64) {
        double s = red[t] + red[64 + t] + red[128 + t] + red[192 + t] + (double)bqkv[h * 192 + t];
        q_mean_s[blockIdx.x * 64 + t] = (float)s;
    }
}

// ---------- fp64-accum 64-col row-GEMM: out[row][0:64] = A_row . Wf + bias ----------
// MODE 0: A row layout = x[(s*B+b)*D+c], row = b*S+s  (q_mean_h)
// MODE 1: A row layout = cpre[row*1024+c]             (ckm)
// 16 rows/block, thread = (dg = t&15 -> 4 d's, sr = t>>4 -> 1 row).
// w chunk fp32 in LDS (16 KB) + x tile (4.4 KB) -> high occupancy; acc[4] ILP.
template<int MODE>
__launch_bounds__(256)
__global__ void rowgemm64_kernel(const float* __restrict__ A, const float* __restrict__ Wf,
                                 const double* __restrict__ bias, double* __restrict__ outp,
                                 int M)
{
    __shared__ float wlds[64 * 64];      // [cc][d]
    __shared__ float xlds[16][68];
    const int t = threadIdx.x;
    const int dg = t & 15, sr = t >> 4;
    const int r0 = blockIdx.x * 16;
    const int row = r0 + sr;
    double acc[4] = {};
    for (int c0 = 0; c0 < 1024; c0 += 64) {
        __syncthreads();
#pragma unroll
        for (int i = 0; i < 4; ++i)
            *(f32x4*)(wlds + t * 4 + i * 1024) =
                *(const f32x4*)(Wf + (size_t)c0 * 64 + t * 4 + i * 1024);
        {
            f32x4 xv = {0.f, 0.f, 0.f, 0.f};
            if (row < M) {
                size_t addr;
                if (MODE == 0) {
                    int b = row >> 11, s = row & (S_ - 1);
                    addr = ((size_t)s * B_ + b) * D_ + c0 + dg * 4;
                } else {
                    addr = (size_t)row * 1024 + c0 + dg * 4;
                }
                xv = *(const f32x4*)(A + addr);
            }
            *(f32x4*)(&xlds[sr][dg * 4]) = xv;
        }
        __syncthreads();
#pragma unroll 8
        for (int cc = 0; cc < 64; ++cc) {
            f32x4 wv = *(const f32x4*)(wlds + cc * 64 + dg * 4);
            float xv = xlds[sr][cc];
#pragma unroll
            for (int j = 0; j < 4; ++j)
                acc[j] += (double)xv * (double)wv[j];
        }
    }
    if (row < M) {
#pragma unroll
        for (int j = 0; j < 4; ++j)
            outp[(size_t)row * 64 + dg * 4 + j] = acc[j] + bias[dg * 4 + j];
    }
}

// ---------------- split-bf16 MFMA GEMM: C = A @ B^T (+bias, epilogues) ----------------
// EPI 0: dual bf16 scatter (q|v): gn<1024 -> Oh(q_hi), else Ol(v_hi). gm = s*4+b.
// EPI 3: single bf16 + lo (k): Oh/Ol at gn. gm = s*4+b.
// EPI 1: c1: relu(v+bias+posdot), 16-row sums -> Cf = t16[(b*128+j)*1024+gn]. gm=b*S+s.
// EPI 2: plain: Cf[gm*1024+gn] = v+bias (guard gm<M).
template<int NPASS, int EPI, bool WLO>
__launch_bounds__(256, 2)
__global__ void mgemm_kernel(const u16* __restrict__ Ah, const u16* __restrict__ Al,
                             const u16* __restrict__ Bh, const u16* __restrict__ Bl,
                             int M, int K, int lda, int ldb,
                             const float* __restrict__ bias,
                             float* __restrict__ Cf,
                             u16* __restrict__ Oh, u16* __restrict__ Ol,
                             const float* __restrict__ pos, const float* __restrict__ w1f)
{
    constexpr int NBUF = (NPASS == 3) ? 4 : 2;
    __shared__ u16 lds[NBUF * 4096];
    u16* ldsAh = lds;
    u16* ldsBh = lds + 4096;
    const int tid = threadIdx.x;
    const int w = tid >> 6, lane = tid & 63;
    const int lq = lane & 15, g = lane >> 4;
    const int wm = (w & 1) * 64, wn = (w >> 1) * 64;
    const int bm = blockIdx.x * 128, bn = blockIdx.y * 128;
    const int i4 = lane >> 2;
    const int kc = (lane & 3) ^ ((lane >> 3) & 3);
    f32x4 acc[4][4] = {};

    const u16* gA = Ah + (size_t)(bm + w * 32 + i4) * lda + kc * 8;
    const u16* gB = Bh + (size_t)(bn + w * 32 + i4) * ldb + kc * 8;
    const u16* gAl = nullptr; const u16* gBl = nullptr;
    u16* ldsAl = nullptr; u16* ldsBl = nullptr;
    if (NPASS == 3) {
        gAl = Al + (size_t)(bm + w * 32 + i4) * lda + kc * 8;
        gBl = Bl + (size_t)(bn + w * 32 + i4) * ldb + kc * 8;
        ldsAl = lds + 8192;
        ldsBl = lds + 12288;
    }
    const int sbase = w * 1024 + lane * 8;

    for (int k0 = 0; k0 < K; k0 += 32) {
        __syncthreads();
        short8 a0 = *(const short8*)(gA + k0);
        short8 a1 = *(const short8*)(gA + 16 * lda + k0);
        short8 b0 = *(const short8*)(gB + k0);
        short8 b1 = *(const short8*)(gB + 16 * ldb + k0);
        short8 al0, al1, bl0, bl1;
        if (NPASS == 3) {
            al0 = *(const short8*)(gAl + k0);
            al1 = *(const short8*)(gAl + 16 * lda + k0);
            bl0 = *(const short8*)(gBl + k0);
            bl1 = *(const short8*)(gBl + 16 * ldb + k0);
        }
        *(short8*)(ldsAh + sbase) = a0;
        *(short8*)(ldsAh + sbase + 512) = a1;
        *(short8*)(ldsBh + sbase) = b0;
        *(short8*)(ldsBh + sbase + 512) = b1;
        if (NPASS == 3) {
            *(short8*)(ldsAl + sbase) = al0;
            *(short8*)(ldsAl + sbase + 512) = al1;
            *(short8*)(ldsBl + sbase) = bl0;
            *(short8*)(ldsBl + sbase + 512) = bl1;
        }
        __syncthreads();
        short8 fa[4], fal[4];
#pragma unroll
        for (int i = 0; i < 4; ++i) {
            int row = wm + i * 16 + lq;
            int sl = row * 4 + (g ^ ((row >> 1) & 3));
            fa[i] = *(const short8*)(ldsAh + sl * 8);
            if (NPASS == 3) fal[i] = *(const short8*)(ldsAl + sl * 8);
        }
#pragma unroll
        for (int jb = 0; jb < 4; ++jb) {
            int row = wn + jb * 16 + lq;
            int sl = row * 4 + (g ^ ((row >> 1) & 3));
            short8 fb = *(const short8*)(ldsBh + sl * 8);
            short8 fbl;
            if (NPASS == 3) fbl = *(const short8*)(ldsBl + sl * 8);
#pragma unroll
            for (int i = 0; i < 4; ++i) {
                acc[i][jb] = __builtin_amdgcn_mfma_f32_16x16x32_bf16(fa[i], fb, acc[i][jb], 0, 0, 0);
                if (NPASS == 3) {
                    acc[i][jb] = __builtin_amdgcn_mfma_f32_16x16x32_bf16(fal[i], fb, acc[i][jb], 0, 0, 0);
                    acc[i][jb] = __builtin_amdgcn_mfma_f32_16x16x32_bf16(fa[i], fbl, acc[i][jb], 0, 0, 0);
                }
            }
        }
    }
    if (EPI == 1) {
        // relu + 16-row partial sums -> t16 (one wave owns each 16-row group)
#pragma unroll
        for (int jb = 0; jb < 4; ++jb) {
            int gn = bn + wn + jb * 16 + lq;
            float bz = bias[gn];
            float w0 = w1f[(size_t)gn * 1027 + 1024];
            float w1 = w1f[(size_t)gn * 1027 + 1025];
            float w2 = w1f[(size_t)gn * 1027 + 1026];
#pragma unroll
            for (int i = 0; i < 4; ++i) {
                int gm0 = bm + wm + i * 16 + g * 4;
                int bb = gm0 >> 11;
                int jj = (gm0 & (S_ - 1)) >> 4;
                float s4 = 0.f;
#pragma unroll
                for (int r = 0; r < 4; ++r) {
                    int st = (gm0 + r) & (S_ - 1);
                    float v = acc[i][jb][r] + bz
                            + pos[st * 3 + 0] * w0 + pos[st * 3 + 1] * w1
                            + pos[st * 3 + 2] * w2;
                    s4 += fmaxf(v, 0.f);
                }
                s4 += __shfl_xor(s4, 16, 64);
                s4 += __shfl_xor(s4, 32, 64);
                if (g == 0) Cf[((size_t)(bb * 128 + jj)) * 1024 + gn] = s4;
            }
        }
    } else {
#pragma unroll
        for (int i = 0; i < 4; ++i) {
#pragma unroll
            for (int jb = 0; jb < 4; ++jb) {
#pragma unroll
                for (int r = 0; r < 4; ++r) {
                    int gm = bm + wm + i * 16 + g * 4 + r;
                    int gn = bn + wn + jb * 16 + lq;
                    float v = acc[i][jb][r] + bias[gn];
                    if (EPI == 0) {
                        int s = gm >> 2, bb = gm & 3;
                        u16 hb = f2bf_u(v);
                        if (gn < 1024) Oh[((size_t)(bb * S_ + s)) * D_ + gn] = hb;
                        else Ol[((size_t)(bb * S_ + s)) * D_ + (gn - 1024)] = hb;
                    } else if (EPI == 3) {
                        int s = gm >> 2, bb = gm & 3;
                        size_t idx = ((size_t)(bb * S_ + s)) * D_ + gn;
                        u16 hb = f2bf_u(v);
                        Oh[idx] = hb;
                        if (WLO) Ol[idx] = f2bf_u(v - bf2f(hb));
                    } else {
                        if (gm < M) Cf[(size_t)gm * 1024 + gn] = v;
                    }
                }
            }
        }
    }
}

// cpre[b,n,c] = (t16[b][n] + t16[b][n+1]) / 32
__global__ void t16c_kernel(const float* __restrict__ t16, float* __restrict__ cpre)
{
    int bn = blockIdx.x;
    int b = bn / NB_, n = bn % NB_;
    for (int c = threadIdx.x; c < 1024; c += 256)
        cpre[(size_t)bn * 1024 + c] =
            (t16[((size_t)(b * 128 + n)) * 1024 + c] +
             t16[((size_t)(b * 128 + n + 1)) * 1024 + c]) * (1.f / 32.f);
}

// v_t[b][h][d][s] = transpose of v_hi[b][s][h*64+d] (bf16 -> bf16)
__launch_bounds__(256)
__global__ void vt_kernel(const u16* __restrict__ v_hi, u16* __restrict__ v_t)
{
    __shared__ u16 tile[64][68];
    int blk = blockIdx.x;
    int b = blk >> 9, h = (blk >> 5) & 15, s0 = (blk & 31) * 64;
    int tid = threadIdx.x;
#pragma unroll
    for (int i = 0; i < 16; ++i) {
        int idx = tid + i * 256;
        int r = idx >> 6, d = idx & 63;
        tile[r][d] = v_hi[((size_t)(b * S_ + s0 + r)) * D_ + h * HD_ + d];
    }
    __syncthreads();
#pragma unroll
    for (int i = 0; i < 16; ++i) {
        int idx = tid + i * 256;
        int d = idx >> 6, cc = idx & 63;
        v_t[((size_t)((b * H_ + h) * HD_ + d)) * S_ + s0 + cc] = tile[cc][d];
    }
}

// out_cmp[b,h,:] = softmax(q_mean_s . cmp_k * SCALE) @ cmp_v
__launch_bounds__(128)
__global__ void out_cmp_kernel(const float* __restrict__ q_mean_s, const float* __restrict__ cmp_k,
                               const float* __restrict__ cmp_v, float* __restrict__ out_cmp)
{
    int bh = blockIdx.x;
    int b = bh >> 4, h = bh & 15;
    int t = threadIdx.x;
    __shared__ float qv[64];
    __shared__ float pv[128];
    __shared__ float red[128];
    if (t < 64) qv[t] = q_mean_s[bh * 64 + t];
    __syncthreads();
    float sc = -1e30f;
    if (t < NB_) {
        const float* kr = &cmp_k[((size_t)b * NB_ + t) * D_ + h * HD_];
        float sum = 0.f;
        for (int d = 0; d < 64; ++d) sum = fmaf(qv[d], kr[d], sum);
        sc = sum * SCALE_;
    }
    red[t] = sc;
    __syncthreads();
    for (int off = 64; off > 0; off >>= 1) {
        if (t < off) red[t] = fmaxf(red[t], red[t + off]);
        __syncthreads();
    }
    float mx = red[0];
    __syncthreads();
    float e = (t < NB_) ? __expf(sc - mx) : 0.f;
    pv[t] = e;
    red[t] = e;
    __syncthreads();
    for (int off = 64; off > 0; off >>= 1) {
        if (t < off) red[t] += red[t + off];
        __syncthreads();
    }
    float sm = red[0];
    __syncthreads();
    if (t < 64) {
        float o = 0.f;
        for (int n = 0; n < NB_; ++n)
            o = fmaf(pv[n], cmp_v[((size_t)b * NB_ + n) * D_ + h * HD_ + t], o);
        out_cmp[bh * 64 + t] = o / sm;
    }
}

// imp_all[b,n,s] = softmax_n(q_mean_h[b,s] . ckm[b,n] * SCALE)  fp64
__launch_bounds__(128)
__global__ void imp1_kernel(const double* __restrict__ q_mean_h, const double* __restrict__ ckm,
                            double* __restrict__ imp_all)
{
    int bs = blockIdx.x;
    int b = bs >> 11, s = bs & (S_ - 1);
    int t = threadIdx.x;
    __shared__ double qv[64];
    __shared__ double red[128];
    if (t < 64) qv[t] = q_mean_h[(size_t)bs * 64 + t];
    __syncthreads();
    double sc = -1e300;
    if (t < NB_) {
        const double* kr = &ckm[(b * NB_ + t) * 64];
        double sum = 0.0;
        for (int d = 0; d < 64; ++d) sum = fma(qv[d], kr[d], sum);
        sc = sum * (double)SCALE_;
    }
    red[t] = sc;
    __syncthreads();
    for (int off = 64; off > 0; off >>= 1) {
        if (t < off) red[t] = fmax(red[t], red[t + off]);
        __syncthreads();
    }
    double mx = red[0];
    __syncthreads();
    double e = (t < NB_) ? exp(sc - mx) : 0.0;
    red[t] = e;
    __syncthreads();
    for (int off = 64; off > 0; off >>= 1) {
        if (t < off) red[t] += red[t + off];
        __syncthreads();
    }
    double sm = red[0];
    if (t < NB_) imp_all[((size_t)(b * NB_ + t)) * S_ + s] = e / sm;
}

// imp[b,n] = mean_s imp_all[b,n,s]  fp64
__global__ void imp2_kernel(const double* __restrict__ imp_all, double* __restrict__ imp)
{
    int bn = blockIdx.x;
    int t = threadIdx.x;
    double sum = 0.0;
    for (int s = t; s < S_; s += 256) sum += imp_all[(size_t)bn * S_ + s];
    __shared__ double red[256];
    red[t] = sum;
    __syncthreads();
    for (int off = 128; off > 0; off >>= 1) {
        if (t < off) red[t] += red[t + off];
        __syncthreads();
    }
    if (t == 0) imp[bn] = red[0] * (1.0 / S_);
}

// exact top-16 per batch, stable (lowest index wins ties)
__global__ void topk_kernel(const double* __restrict__ imp, int* __restrict__ topb)
{
    int b = threadIdx.x;
    if (b >= B_) return;
    unsigned long long used0 = 0ull, used1 = 0ull;
    for (int m = 0; m < NSEL_; ++m) {
        double best = -1e300;
        int bi = 0;
        for (int n = 0; n < NB_; ++n) {
            bool u = (n < 64) ? ((used0 >> n) & 1ull) : ((used1 >> (n - 64)) & 1ull);
            double v = imp[b * NB_ + n];
            if (!u && v > best) { best = v; bi = n; }
        }
        if (bi < 64) used0 |= 1ull << bi; else used1 |= 1ull << (bi - 64);
        topb[b * NSEL_ + m] = bi;
    }
}

// ---------------- MFMA flash attention (bf16 inputs) ----------------
template<int NCH, int MODE>
__launch_bounds__(256, 4)
__global__ void attn_mfma_kernel(const u16* __restrict__ q_hi, const u16* __restrict__ k_hi,
                                 const u16* __restrict__ v_t,
                                 const int* __restrict__ topb, float* __restrict__ outp)
{
    __shared__ __attribute__((aligned(16))) char smem[27648];
    u16* klds = (u16*)smem;
    u16* vlds = (u16*)(smem + 9216);
    u16* plds = (u16*)(smem + 18432);
    __shared__ int selb[NSEL_];
    const int tid = threadIdx.x;
    const int wid = tid >> 6, lane = tid & 63;
    const int lq = lane & 15, g = lane >> 4;
    const int blk = blockIdx.x;
    const int b = blk >> 9;
    const int h = (blk >> 5) & 15;
    const int q0 = (blk & 31) * 64 + wid * 16;
    u16* pw = plds + wid * 16 * 72;

    if (MODE == 1 && tid < NSEL_) selb[tid] = topb[b * NSEL_ + tid];

    short8 qfrag[2];
    {
        const u16* qp = q_hi + ((size_t)(b * S_ + q0 + lq)) * D_ + h * HD_ + g * 8;
        qfrag[0] = *(const short8*)qp;
        qfrag[1] = *(const short8*)(qp + 32);
    }
    f32x4 oacc[4] = {};
    float rm = -1e30f, rl = 0.f;

    for (int c = 0; c < NCH; ++c) {
        __syncthreads();
        int t0;
        bool clamped = false;
        if (MODE == 0) t0 = S_ - NCH * 64 + c * 64;
        else { t0 = selb[c] * SELBLK_; clamped = (t0 >= S_); }
#pragma unroll
        for (int it = 0; it < 2; ++it) {
            int idx = tid + it * 256;
            int r = idx >> 3, cc = idx & 7;
            int tk = t0 + r; if (tk > S_ - 1) tk = S_ - 1;
            *(short8*)(klds + r * 72 + cc * 8) =
                *(const short8*)(k_hi + ((size_t)(b * S_ + tk)) * D_ + h * HD_ + cc * 8);
            const u16* vrow = v_t + ((size_t)((b * H_ + h) * HD_ + r)) * S_;
            short8 vv;
            if (!clamped) {
                vv = *(const short8*)(vrow + t0 + cc * 8);
            } else {
                short x = (short)vrow[S_ - 1];
                vv = (short8){x, x, x, x, x, x, x, x};
            }
            *(short8*)(vlds + r * 72 + cc * 8) = vv;
        }
        __syncthreads();
        f32x4 st[4];
#pragma unroll
        for (int sub = 0; sub < 4; ++sub) {
            short8 ka0 = *(const short8*)(klds + (sub * 16 + lq) * 72 + g * 8);
            short8 ka1 = *(const short8*)(klds + (sub * 16 + lq) * 72 + 32 + g * 8);
            f32x4 acc = {};
            acc = __builtin_amdgcn_mfma_f32_16x16x32_bf16(ka0, qfrag[0], acc, 0, 0, 0);
            acc = __builtin_amdgcn_mfma_f32_16x16x32_bf16(ka1, qfrag[1], acc, 0, 0, 0);
            st[sub] = acc;
        }
        float mx = -1e30f;
#pragma unroll
        for (int sub = 0; sub < 4; ++sub)
#pragma unroll
            for (int r = 0; r < 4; ++r) {
                st[sub][r] *= SCALE_;
                mx = fmaxf(mx, st[sub][r]);
            }
        mx = fmaxf(mx, __shfl_xor(mx, 16, 64));
        mx = fmaxf(mx, __shfl_xor(mx, 32, 64));
        float nm = fmaxf(rm, mx);
        float alpha = __expf(rm - nm);
        rm = nm;
        float ps = 0.f;
#pragma unroll
        for (int sub = 0; sub < 4; ++sub)
#pragma unroll
            for (int r = 0; r < 4; ++r) {
                float p = __expf(st[sub][r] - nm);
                st[sub][r] = p;
                ps += p;
            }
        ps += __shfl_xor(ps, 16, 64);
        ps += __shfl_xor(ps, 32, 64);
        rl = rl * alpha + ps;
#pragma unroll
        for (int m = 0; m < 4; ++m)
#pragma unroll
            for (int r = 0; r < 4; ++r) oacc[m][r] *= alpha;
#pragma unroll
        for (int sub = 0; sub < 4; ++sub)
#pragma unroll
            for (int r = 0; r < 4; ++r)
                pw[lq * 72 + sub * 16 + g * 4 + r] = f2bf_u(st[sub][r]);
        short8 pf0 = *(const short8*)(pw + lq * 72 + g * 8);
        short8 pf1 = *(const short8*)(pw + lq * 72 + 32 + g * 8);
#pragma unroll
        for (int m = 0; m < 4; ++m) {
            short8 va0 = *(const short8*)(vlds + (m * 16 + lq) * 72 + g * 8);
            short8 va1 = *(const short8*)(vlds + (m * 16 + lq) * 72 + 32 + g * 8);
            oacc[m] = __builtin_amdgcn_mfma_f32_16x16x32_bf16(va0, pf0, oacc[m], 0, 0, 0);
            oacc[m] = __builtin_amdgcn_mfma_f32_16x16x32_bf16(va1, pf1, oacc[m], 0, 0, 0);
        }
    }
    __syncthreads();
    float invl = 1.f / rl;
    float* obuf = (float*)smem + wid * (16 * 68);
#pragma unroll
    for (int m = 0; m < 4; ++m)
#pragma unroll
        for (int r = 0; r < 4; ++r)
            obuf[lq * 68 + m * 16 + g * 4 + r] = oacc[m][r] * invl;
    {
        int q = lane >> 2, seg = lane & 3;
        const float* row = obuf + q * 68 + seg * 16;
        float* dst = outp + ((size_t)(b * S_ + q0 + q)) * D_ + h * HD_ + seg * 16;
#pragma unroll
        for (int k = 0; k < 4; ++k)
            *(f32x4*)(dst + k * 4) = *(const f32x4*)(row + k * 4);
    }
}

// gates = softmax([oc,osl,ow] @ w_g.T + b_g); out = g0*oc+g1*osl+g2*ow
__launch_bounds__(128)
__global__ void gate_kernel(const float* __restrict__ out_cmp, const float* __restrict__ o_slc,
                            const float* __restrict__ o_win, const float* __restrict__ w_g,
                            const float* __restrict__ b_g, float* __restrict__ outp)
{
    int bs = blockIdx.x;
    int b = bs >> 11;
    int t = threadIdx.x;
    float oc_r[8], os_r[8], ow_r[8];
    float g0 = 0.f, g1 = 0.f, g2 = 0.f;
#pragma unroll
    for (int i = 0; i < 8; ++i) {
        int c = t + i * 128;
        float oc = out_cmp[(b * H_ + (c >> 6)) * 64 + (c & 63)];
        float os = o_slc[(size_t)bs * D_ + c];
        float ow = o_win[(size_t)bs * D_ + c];
        oc_r[i] = oc; os_r[i] = os; ow_r[i] = ow;
        g0 += w_g[c] * oc + w_g[1024 + c] * os + w_g[2048 + c] * ow;
        g1 += w_g[3072 + c] * oc + w_g[3072 + 1024 + c] * os + w_g[3072 + 2048 + c] * ow;
        g2 += w_g[6144 + c] * oc + w_g[6144 + 1024 + c] * os + w_g[6144 + 2048 + c] * ow;
    }
    __shared__ float red[3][128];
    red[0][t] = g0; red[1][t] = g1; red[2][t] = g2;
    __syncthreads();
    for (int off = 64; off > 0; off >>= 1) {
        if (t < off) {
            red[0][t] += red[0][t + off];
            red[1][t] += red[1][t + off];
            red[2][t] += red[2][t + off];
        }
        __syncthreads();
    }
    float a0 = red[0][0] + b_g[0], a1 = red[1][0] + b_g[1], a2 = red[2][0] + b_g[2];
    float m = fmaxf(a0, fmaxf(a1, a2));
    float e0 = __expf(a0 - m), e1 = __expf(a1 - m), e2 = __expf(a2 - m);
    float inv = 1.f / (e0 + e1 + e2);
    e0 *= inv; e1 *= inv; e2 *= inv;
#pragma unroll
    for (int i = 0; i < 8; ++i) {
        int c = t + i * 128;
        outp[(size_t)bs * D_ + c] = e0 * oc_r[i] + e1 * os_r[i] + e2 * ow_r[i];
    }
}

extern "C" void kernel_launch(void* const* d_in, const int* in_sizes, int n_in,
                              void* d_out, int out_size, void* d_ws, size_t ws_size,
                              hipStream_t stream)
{
    const float* x     = (const float*)d_in[0];
    const float* pos   = (const float*)d_in[1];
    const float* w_qkv = (const float*)d_in[2];
    const float* b_qkv = (const float*)d_in[3];
    const float* w_c1  = (const float*)d_in[4];
    const float* b_c1  = (const float*)d_in[5];
    const float* w_c2  = (const float*)d_in[6];
    const float* b_c2  = (const float*)d_in[7];
    const float* w_g   = (const float*)d_in[8];
    const float* b_g   = (const float*)d_in[9];
    float* out = (float*)d_out;
    (void)in_sizes; (void)n_in; (void)out_size; (void)ws_size;

    char* wp = (char*)d_ws;
    size_t off = 0;
    auto alloc = [&](size_t nbytes) -> void* {
        void* p = (void*)(wp + off);
        off += ((nbytes + 255) / 256) * 256;
        return p;
    };
    const size_t NTOK = (size_t)B_ * S_ * D_;
    float* o_slc = (float*)alloc(NTOK * 4);
    float* o_win = (float*)alloc(NTOK * 4);            // early life: imp_all (fp64)
    double* imp_all = (double*)o_win;
    u16* q_hi = (u16*)alloc(NTOK * 2);
    u16* k_hi = (u16*)alloc(NTOK * 2);
    u16* k_lo = (u16*)alloc(NTOK * 2);
    u16* v_hi = (u16*)alloc(NTOK * 2);
    u16* x_hi = (u16*)alloc(NTOK * 2);                 // late life: v_t
    u16* v_t  = x_hi;
    u16* x_lo = (u16*)alloc(NTOK * 2);                 // late life: misc region
    // malloc2 region aliases x_lo. INVARIANT: nothing here may be WRITTEN
    // before the NPASS3 k-GEMM (the last reader of x_lo) has run.
    char* mp = (char*)x_lo;
    size_t moff = 0;
    auto malloc2 = [&](size_t nbytes) -> void* {
        void* p = (void*)(mp + moff);
        moff += ((nbytes + 255) / 256) * 256;
        return p;
    };
    const size_t NCMP = (size_t)B_ * NB_ * D_;
    float* cpre_k = (float*)malloc2(NCMP * 4);
    float* cpre_v = (float*)malloc2(NCMP * 4);
    float* cmp_k  = (float*)malloc2(NCMP * 4);
    float* cmp_v  = (float*)malloc2(NCMP * 4);
    u16* cpk_hi = (u16*)malloc2(NCMP * 2);
    u16* cpv_hi = (u16*)malloc2(NCMP * 2);
    float*  t16  = (float*)malloc2((size_t)B_ * 128 * 1024 * 4);
    double* ckm  = (double*)malloc2(B_ * NB_ * 64 * 8);
    float*  ocmp = (float*)malloc2(B_ * H_ * 64 * 4);
    double* imp  = (double*)malloc2(B_ * NB_ * 8);
    int*    topb = (int*)malloc2(B_ * NSEL_ * 4);
    malloc2(65536);
    // weights / fp64 helpers (live across whole pipeline; written in step 0 —
    // must NOT alias x_lo).
    u16* wq_hi = (u16*)alloc((size_t)3072 * 1024 * 2);
    u16* wq_lo = (u16*)alloc((size_t)3072 * 1024 * 2);
    float* b_perm = (float*)alloc(3072 * 4);
    u16* w1h = (u16*)alloc((size_t)1024 * 1032 * 2);
    u16* w1l = (u16*)alloc((size_t)1024 * 1032 * 2);
    u16* w2h = (u16*)alloc((size_t)1024 * 1024 * 2);
    double* q_mean_h = (double*)alloc((size_t)B_ * S_ * 64 * 8);
    float* wqm_f = (float*)alloc((size_t)1024 * 64 * 4);
    double* bqm  = (double*)alloc(64 * 8);
    float* w2m_f = (float*)alloc((size_t)1024 * 64 * 4);
    double* b2m  = (double*)alloc(64 * 8);
    double* x_mean = (double*)alloc((size_t)B_ * 1024 * 8);
    double* xpart  = (double*)alloc((size_t)B_ * 64 * 1024 * 8);
    float*  q_mean_s = (float*)alloc(B_ * H_ * 64 * 4);
    alloc(65536);

    dim3 blk(256);
    // 0. weight prep + splits + fp64 means helpers
    split_kernel<<<(int)(NTOK / 1024), blk, 0, stream>>>(x, x_hi, x_lo, (int)(NTOK / 4));
    wqkv_prep_kernel<<<3072, blk, 0, stream>>>(w_qkv, b_qkv, wq_hi, wq_lo, b_perm);
    w1_split_kernel<<<1024, blk, 0, stream>>>(w_c1, w1h, w1l);
    split_kernel<<<1024, blk, 0, stream>>>(w_c2, w2h, nullptr, 1024 * 1024 / 4);
    wqm_prep_kernel<<<1024, 64, 0, stream>>>(w_qkv, b_qkv, wqm_f, bqm);
    w2m_prep_kernel<<<1024, 64, 0, stream>>>(w_c2, b_c2, w2m_f, b2m);
    xmean1_kernel<<<B_ * 64, blk, 0, stream>>>(x, xpart);
    xmean2_kernel<<<B_, blk, 0, stream>>>(xpart, x_mean);
    qms_kernel<<<B_ * H_, blk, 0, stream>>>(x_mean, w_qkv, b_qkv, q_mean_s);
    rowgemm64_kernel<0><<<512, blk, 0, stream>>>(x, wqm_f, bqm, q_mean_h, B_ * S_);
    // 1. QKV projection: q|v fused NPASS1, k NPASS3
    mgemm_kernel<1, 0, false><<<dim3(64, 16), blk, 0, stream>>>(
        x_hi, nullptr, wq_hi, nullptr, S_ * B_, 1024, 1024, 1024,
        b_perm, nullptr, q_hi, v_hi, nullptr, nullptr);
    mgemm_kernel<3, 3, true><<<dim3(64, 8), blk, 0, stream>>>(
        x_hi, x_lo, wq_hi + (size_t)2048 * 1024, wq_lo + (size_t)2048 * 1024, S_ * B_, 1024, 1024, 1024,
        b_perm + 2048, nullptr, k_hi, k_lo, nullptr, nullptr);
    // 1b. V^T for attention (x_hi dead -> v_t alias)
    vt_kernel<<<2048, blk, 0, stream>>>(v_hi, v_t);
    // 2. compression: c1 with fused relu+16-row-sum epilogue -> t16 -> cpre
    mgemm_kernel<3, 1, false><<<dim3(64, 8), blk, 0, stream>>>(
        k_hi, k_lo, w1h, w1l, B_ * S_, 1024, 1024, 1032,
        b_c1, t16, nullptr, nullptr, pos, w_c1);
    t16c_kernel<<<B_ * NB_, blk, 0, stream>>>(t16, cpre_k);
    mgemm_kernel<1, 1, false><<<dim3(64, 8), blk, 0, stream>>>(
        v_hi, nullptr, w1h, nullptr, B_ * S_, 1024, 1024, 1032,
        b_c1, t16, nullptr, nullptr, pos, w_c1);
    t16c_kernel<<<B_ * NB_, blk, 0, stream>>>(t16, cpre_v);
    split_kernel<<<508, blk, 0, stream>>>(cpre_k, cpk_hi, nullptr, (int)(NCMP / 4));
    split_kernel<<<508, blk, 0, stream>>>(cpre_v, cpv_hi, nullptr, (int)(NCMP / 4));
    mgemm_kernel<1, 2, false><<<dim3(4, 8), blk, 0, stream>>>(
        cpk_hi, nullptr, w2h, nullptr, B_ * NB_, 1024, 1024, 1024,
        b_c2, cmp_k, nullptr, nullptr, nullptr, nullptr);
    mgemm_kernel<1, 2, false><<<dim3(4, 8), blk, 0, stream>>>(
        cpv_hi, nullptr, w2h, nullptr, B_ * NB_, 1024, 1024, 1024,
        b_c2, cmp_v, nullptr, nullptr, nullptr, nullptr);
    // 3. ckm (fp64 accum, fp32 weights, from cpre_k directly)
    rowgemm64_kernel<1><<<32, blk, 0, stream>>>(cpre_k, w2m_f, b2m, ckm, B_ * NB_);
    // 4. compressed-branch attention + importance (fp64) + top-k
    out_cmp_kernel<<<B_ * H_, 128, 0, stream>>>(q_mean_s, cmp_k, cmp_v, ocmp);
    imp1_kernel<<<B_ * S_, 128, 0, stream>>>(q_mean_h, ckm, imp_all);
    imp2_kernel<<<B_ * NB_, 256, 0, stream>>>(imp_all, imp);
    topk_kernel<<<1, 64, 0, stream>>>(imp, topb);
    // 5. selected + window attention (MFMA flash, bf16)
    attn_mfma_kernel<16, 1><<<2048, blk, 0, stream>>>(q_hi, k_hi, v_t, topb, o_slc);
    attn_mfma_kernel<8, 0><<<2048, blk, 0, stream>>>(q_hi, k_hi, v_t, nullptr, o_win);
    // 6. gate + combine
    gate_kernel<<<B_ * S_, 128, 0, stream>>>(ocmp, o_slc, o_win, w_g, b_g, out);
}